// Round 1
// baseline (1868.150 us; speedup 1.0000x reference)
//
#include <hip/hip_runtime.h>

// EmbeddingRNN: e = emb[x]; xz = e@W + b; 16-step LSTM recurrence z = xz_t + h@U
// Shapes: x (64,128,16) int32, emb (155,256) f32, W (256,1024) f32, U (256,1024) f32,
//         b (1024) f32, out (64,128,256) f32.
// Structure: 8192 independent rows (b*128+s). Block owns RTILE=16 rows for the whole
// 16-step sequence: h,c stay on-CU (LDS/regs), no workspace, no grid sync.
// Per step: z[r, g*256+d] = b + sum_k e_t[r,k]*W[k,g*256+d] + h[r,k]*U[k,g*256+d]
// Thread tid owns d=tid across all 4 gates and all 16 rows -> acc[16][4].

#define NROWS   8192
#define DD      256
#define GDIM    1024
#define C_STEPS 16
#define RTILE   16
#define BLOCK   256

__global__ __launch_bounds__(BLOCK, 2)
void lstm_fused_f32(const int* __restrict__ x,
                    const float* __restrict__ emb,
                    const float* __restrict__ W,
                    const float* __restrict__ U,
                    const float* __restrict__ b,
                    float* __restrict__ out)
{
    __shared__ float e_lds[RTILE][DD];
    __shared__ float h_lds[RTILE][DD];

    const int tid  = threadIdx.x;
    const int base = blockIdx.x * RTILE;

    // per-thread cell state for d=tid, all 16 rows
    float c[RTILE];
#pragma unroll
    for (int r = 0; r < RTILE; ++r) c[r] = 0.f;

    float bb[4];
#pragma unroll
    for (int g = 0; g < 4; ++g) bb[g] = b[g * DD + tid];

    // zero h, stage e for t=0
#pragma unroll
    for (int r = 0; r < RTILE; ++r) h_lds[r][tid] = 0.f;
    {
        const int r = tid >> 4, seg = tid & 15;
        const int idx = x[(base + r) * C_STEPS + 0];
        const float4* src = (const float4*)(emb + idx * DD + seg * 16);
        float4* dst = (float4*)(&e_lds[r][seg * 16]);
#pragma unroll
        for (int i = 0; i < 4; ++i) dst[i] = src[i];
    }
    __syncthreads();

    const float* Wp = W + tid;
    const float* Up = U + tid;

    for (int t = 0; t < C_STEPS; ++t) {
        float acc[RTILE][4];
#pragma unroll
        for (int r = 0; r < RTILE; ++r)
#pragma unroll
            for (int g = 0; g < 4; ++g) acc[r][g] = 0.f;

        // K loop: 256 deep, unroll by 4. Weights coalesced from L1/L2 (L2-resident),
        // e/h as float4 LDS broadcasts (same addr across lanes -> conflict-free).
        for (int k = 0; k < DD; k += 4) {
            float w[4][4], u[4][4];
#pragma unroll
            for (int kk = 0; kk < 4; ++kk) {
                const float* wr = Wp + (k + kk) * GDIM;
                const float* ur = Up + (k + kk) * GDIM;
#pragma unroll
                for (int g = 0; g < 4; ++g) {
                    w[kk][g] = wr[g * DD];
                    u[kk][g] = ur[g * DD];
                }
            }
#pragma unroll
            for (int r = 0; r < RTILE; ++r) {
                const float4 e4 = *(const float4*)&e_lds[r][k];
                const float4 h4 = *(const float4*)&h_lds[r][k];
#pragma unroll
                for (int g = 0; g < 4; ++g) {
                    float a = acc[r][g];
                    a += e4.x * w[0][g];
                    a += h4.x * u[0][g];
                    a += e4.y * w[1][g];
                    a += h4.y * u[1][g];
                    a += e4.z * w[2][g];
                    a += h4.z * u[2][g];
                    a += e4.w * w[3][g];
                    a += h4.w * u[3][g];
                    acc[r][g] = a;
                }
            }
        }
        __syncthreads();  // all reads of e_lds/h_lds done before overwrite

        // gate update (Keras order i,f,g,o; identity candidate/output activations)
#pragma unroll
        for (int r = 0; r < RTILE; ++r) {
            const float zi = acc[r][0] + bb[0];
            const float zf = acc[r][1] + bb[1];
            const float zg = acc[r][2] + bb[2];
            const float zo = acc[r][3] + bb[3];
            const float ig = 1.f / (1.f + __expf(-zi));
            const float fg = 1.f / (1.f + __expf(-zf));
            const float og = 1.f / (1.f + __expf(-zo));
            const float cn = fg * c[r] + ig * zg;
            c[r] = cn;
            const float h = og * cn;
            h_lds[r][tid] = h;
            if (t == C_STEPS - 1) out[(base + r) * DD + tid] = h;
        }
        // stage e for t+1 (overlapped with gate phase)
        if (t < C_STEPS - 1) {
            const int r = tid >> 4, seg = tid & 15;
            const int idx = x[(base + r) * C_STEPS + (t + 1)];
            const float4* src = (const float4*)(emb + idx * DD + seg * 16);
            float4* dst = (float4*)(&e_lds[r][seg * 16]);
#pragma unroll
            for (int i = 0; i < 4; ++i) dst[i] = src[i];
        }
        __syncthreads();
    }
}

extern "C" void kernel_launch(void* const* d_in, const int* in_sizes, int n_in,
                              void* d_out, int out_size, void* d_ws, size_t ws_size,
                              hipStream_t stream) {
    const int*   x   = (const int*)d_in[0];
    const float* emb = (const float*)d_in[1];
    const float* W   = (const float*)d_in[2];
    const float* U   = (const float*)d_in[3];
    const float* b   = (const float*)d_in[4];
    float* out = (float*)d_out;

    lstm_fused_f32<<<NROWS / RTILE, BLOCK, 0, stream>>>(x, emb, W, U, b, out);
}

// Round 2
// 246.676 us; speedup vs baseline: 7.5733x; 7.5733x over previous
//
#include <hip/hip_runtime.h>
#include <hip/hip_bf16.h>

// EmbeddingRNN via MFMA:
//   phase 0a: embW[i,:] = emb[i,:] @ W + b      (155 x 1024 f32, tiny GEMM)
//   phase 0b: Upack = U cast to bf16, packed MFMA-fragment-major per wave slice
//   phase 1:  per block (32 rows, all 16 steps): z = embW[x_t] (gather) + h @ U (MFMA),
//             LSTM gate update wave-local, h double-buffered in LDS (f32, XOR-swizzled).
// Only the recurrent matmul runs in bf16 (h and U); everything else stays f32.

#define DD      256
#define G4      1024
#define NCHAR   155
#define TSTEPS  16
#define RTILE   32
#define NROWS   8192
#define NBLOCKS (NROWS / RTILE)   // 256
#define NTHREADS 512              // 8 waves; wave w owns d-slice [w*32, w*32+32)

typedef __attribute__((ext_vector_type(8))) short bf16x8;
typedef __attribute__((ext_vector_type(4))) float f32x4;

__device__ inline short f2bf(float f) {
    __hip_bfloat16 h = __float2bfloat16(f);   // RTNE
    return *reinterpret_cast<short*>(&h);
}

// ---------------- phase 0a: embW = emb @ W + b ----------------
__global__ __launch_bounds__(256)
void embw_kernel(const float* __restrict__ emb, const float* __restrict__ W,
                 const float* __restrict__ b, float* __restrict__ embW) {
    const int i   = blockIdx.x;      // 0..154
    const int tid = threadIdx.x;     // owns col tid + g*256
    float a0 = b[tid], a1 = b[256 + tid], a2 = b[512 + tid], a3 = b[768 + tid];
    const float* er = emb + i * DD;
    for (int k = 0; k < DD; ++k) {
        const float e = er[k];                    // wave-uniform -> s_load
        const float* wr = W + k * G4 + tid;       // coalesced
        a0 += e * wr[0];
        a1 += e * wr[256];
        a2 += e * wr[512];
        a3 += e * wr[768];
    }
    float* o = embW + i * G4 + tid;
    o[0] = a0; o[256] = a1; o[512] = a2; o[768] = a3;
}

// ---------------- phase 0b: pack U into bf16 MFMA B-fragments ----------------
// Fragment for mfma_f32_16x16x32_bf16 B: lane l holds B[k0+(l>>4)*8+j][col0+(l&15)], j=0..7.
// Layout: up[((w*8 + kt)*8 + nt)*64 + lane] (bf16x8), nt = g*2 + nn,
//         col0 = g*256 + w*32 + nn*16, k0 = kt*32.
__global__ __launch_bounds__(256)
void upack_kernel(const float* __restrict__ U, bf16x8* __restrict__ up) {
    const int gid  = blockIdx.x * 256 + threadIdx.x;   // 32768 total
    const int lane = gid & 63;
    const int nt   = (gid >> 6) & 7;
    const int kt   = (gid >> 9) & 7;
    const int w    = gid >> 12;
    const int g = nt >> 1, nn = nt & 1;
    const int col = g * 256 + w * 32 + nn * 16 + (lane & 15);
    const int k0  = kt * 32 + (lane >> 4) * 8;
    bf16x8 v;
#pragma unroll
    for (int j = 0; j < 8; ++j) v[j] = f2bf(U[(k0 + j) * G4 + col]);
    up[gid] = v;
}

// ---------------- phase 1: fused recurrence ----------------
__global__ __launch_bounds__(NTHREADS, 2)
void lstm_mfma(const int* __restrict__ x, const float* __restrict__ embW,
               const bf16x8* __restrict__ up, float* __restrict__ out) {
    // h double-buffered, f32, XOR-swizzled: float index idx ^ ((row&15)<<2)
    // spreads the 1KB row stride across banks (2-way max on both rd & wr).
    __shared__ float hbuf[2][RTILE * DD];   // 2 x 32KB
    __shared__ int   xs[RTILE * TSTEPS];    // 2KB

    const int tid  = threadIdx.x;
    const int w    = tid >> 6;
    const int lane = tid & 63;
    const int l15  = lane & 15, lg = lane >> 4;
    const int base = blockIdx.x * RTILE;

    xs[tid] = x[base * TSTEPS + tid];       // 512 ints, coalesced

    f32x4 acc[2][8];                        // [mt][nt = g*2+nn], 64 f32
    float c[16];                            // [mt*8 + nn*4 + j]
#pragma unroll
    for (int i = 0; i < 16; ++i) c[i] = 0.f;

    const bf16x8* upw = up + w * 4096;      // this wave's packed U slice (64KB)

    __syncthreads();

    for (int t = 0; t < TSTEPS; ++t) {
        // ---- acc init: z = embW[x_t] gather (includes +b) ----
#pragma unroll
        for (int mt = 0; mt < 2; ++mt) {
#pragma unroll
            for (int j = 0; j < 4; ++j) {
                const int r    = mt * 16 + lg * 4 + j;       // C/D row = (lane>>4)*4+j
                const int xrow = xs[r * TSTEPS + t];
                const float* ew = embW + xrow * G4 + w * 32 + l15;
#pragma unroll
                for (int nt = 0; nt < 8; ++nt)
                    acc[mt][nt][j] = ew[(nt >> 1) * 256 + (nt & 1) * 16];
            }
        }

        // ---- z += h @ U via MFMA (skip at t=0: h=0) ----
        if (t > 0) {
            const float* rb = hbuf[(t - 1) & 1];
#pragma unroll
            for (int kt = 0; kt < 8; ++kt) {
                bf16x8 bfr[8];
#pragma unroll
                for (int nt = 0; nt < 8; ++nt)
                    bfr[nt] = upw[(kt * 8 + nt) * 64 + lane];   // coalesced dwordx4, L2

                bf16x8 afr[2];
#pragma unroll
                for (int mt = 0; mt < 2; ++mt) {
                    const int row = mt * 16 + l15;              // A row = lane&15
                    const int kb  = kt * 32 + lg * 8;           // A k = (lane>>4)*8+j
                    const int sw  = (row & 15) << 2;
                    const float4 f0 = *(const float4*)&rb[(row * DD + kb) ^ sw];
                    const float4 f1 = *(const float4*)&rb[(row * DD + kb + 4) ^ sw];
                    bf16x8 a;
                    a[0] = f2bf(f0.x); a[1] = f2bf(f0.y); a[2] = f2bf(f0.z); a[3] = f2bf(f0.w);
                    a[4] = f2bf(f1.x); a[5] = f2bf(f1.y); a[6] = f2bf(f1.z); a[7] = f2bf(f1.w);
                    afr[mt] = a;
                }
#pragma unroll
                for (int mt = 0; mt < 2; ++mt)
#pragma unroll
                    for (int nt = 0; nt < 8; ++nt)
                        acc[mt][nt] = __builtin_amdgcn_mfma_f32_16x16x32_bf16(
                            afr[mt], bfr[nt], acc[mt][nt], 0, 0, 0);
            }
        }

        // ---- gate update (Keras i,f,g,o; identity candidate/output) ----
        float* wb = hbuf[t & 1];
#pragma unroll
        for (int mt = 0; mt < 2; ++mt) {
#pragma unroll
            for (int nn = 0; nn < 2; ++nn) {
#pragma unroll
                for (int j = 0; j < 4; ++j) {
                    const float zi = acc[mt][0 + nn][j];
                    const float zf = acc[mt][2 + nn][j];
                    const float zg = acc[mt][4 + nn][j];
                    const float zo = acc[mt][6 + nn][j];
                    const float ig = 1.f / (1.f + __expf(-zi));
                    const float fg = 1.f / (1.f + __expf(-zf));
                    const float og = 1.f / (1.f + __expf(-zo));
                    const int   ci = mt * 8 + nn * 4 + j;
                    const float cn = fg * c[ci] + ig * zg;
                    c[ci] = cn;
                    const float h = og * cn;
                    const int row = mt * 16 + lg * 4 + j;
                    const int d   = w * 32 + nn * 16 + l15;
                    wb[(row * DD + d) ^ ((row & 15) << 2)] = h;
                    if (t == TSTEPS - 1) out[(base + row) * DD + d] = h;
                }
            }
        }
        __syncthreads();   // one barrier/step: h writes visible, prev reads done
    }
}

extern "C" void kernel_launch(void* const* d_in, const int* in_sizes, int n_in,
                              void* d_out, int out_size, void* d_ws, size_t ws_size,
                              hipStream_t stream) {
    const int*   x   = (const int*)d_in[0];
    const float* emb = (const float*)d_in[1];
    const float* W   = (const float*)d_in[2];
    const float* U   = (const float*)d_in[3];
    const float* b   = (const float*)d_in[4];
    float* out = (float*)d_out;

    float*  embW = (float*)d_ws;                          // 155*1024*4 = 620KB
    bf16x8* up   = (bf16x8*)((char*)d_ws + (1 << 20));    // 512KB at +1MB

    embw_kernel<<<NCHAR, 256, 0, stream>>>(emb, W, b, embW);
    upack_kernel<<<128, 256, 0, stream>>>(U, up);
    lstm_mfma<<<NBLOCKS, NTHREADS, 0, stream>>>(x, embW, up, out);
}